// Round 1
// baseline (466.194 us; speedup 1.0000x reference)
//
#include <hip/hip_runtime.h>
#include <math.h>

// SSIM loss for X,Y: (32,3,512,512) fp32, 11x11 sigma=1.5 Gaussian, VALID conv.
// Output: scalar float = 1 - mean(ssim_map).  Mean over (C,H,W) per image then
// over images == global mean (equal counts per image).
//
// Strategy: separable Gaussian. Per 32x32 output tile:
//   1. stage 42x42 X,Y input tile in LDS
//   2. horizontal 11-tap pass -> 5 fields (m1, m2, x2, y2, xy) in LDS
//   3. vertical 11-tap pass + SSIM pointwise + per-thread accumulate
//   4. block reduce -> one atomicAdd(double) per block
// Finalize kernel writes 1 - sum/count.

#define WIN   11
#define TO    32            // output tile edge
#define TI    (TO + WIN - 1) // 42 input tile edge
#define IMG_H 512
#define IMG_W 512
#define OUT_H 502
#define OUT_W 502
#define C1F   6.5025f       // (0.01*255)^2
#define C2F   58.5225f      // (0.03*255)^2

struct GaussW { float w[WIN]; };

__global__ __launch_bounds__(256) void ssim_tile_kernel(
    const float* __restrict__ X, const float* __restrict__ Y,
    GaussW gw, double* __restrict__ acc)
{
    __shared__ float xs[TI][TI + 2];   // +2 pad: keep rows off power-of-2 stride
    __shared__ float ys[TI][TI + 2];
    __shared__ float hb[5][TI][TO];    // horizontal-pass results

    const int plane = blockIdx.z;               // 0..95 (n*3+c)
    const int ox0 = blockIdx.x * TO;
    const int oy0 = blockIdx.y * TO;
    const float* Xp = X + (size_t)plane * IMG_H * IMG_W;
    const float* Yp = Y + (size_t)plane * IMG_H * IMG_W;
    const int tid = threadIdx.x;

    // ---- 1. stage input tile (clamped loads; clamped data never feeds a
    //         valid output: gi<502 => rows used <= 511) ----
    for (int idx = tid; idx < TI * TI; idx += 256) {
        int r = idx / TI, c = idx - r * TI;
        int gr = oy0 + r; if (gr > IMG_H - 1) gr = IMG_H - 1;
        int gc = ox0 + c; if (gc > IMG_W - 1) gc = IMG_W - 1;
        size_t off = (size_t)gr * IMG_W + gc;
        xs[r][c] = Xp[off];
        ys[r][c] = Yp[off];
    }
    __syncthreads();

    // ---- 2. horizontal pass: TI rows x TO cols ----
    for (int idx = tid; idx < TI * TO; idx += 256) {
        int r = idx / TO, c = idx - r * TO;
        float m1 = 0.f, m2 = 0.f, s11 = 0.f, s22 = 0.f, s12 = 0.f;
#pragma unroll
        for (int k = 0; k < WIN; ++k) {
            float wv = gw.w[k];
            float x = xs[r][c + k];
            float y = ys[r][c + k];
            m1  += wv * x;
            m2  += wv * y;
            s11 += wv * x * x;
            s22 += wv * y * y;
            s12 += wv * x * y;
        }
        hb[0][r][c] = m1;
        hb[1][r][c] = m2;
        hb[2][r][c] = s11;
        hb[3][r][c] = s22;
        hb[4][r][c] = s12;
    }
    __syncthreads();

    // ---- 3. vertical pass + SSIM pointwise ----
    float psum = 0.f;
    for (int idx = tid; idx < TO * TO; idx += 256) {
        int i = idx / TO, c = idx - i * TO;
        int gi = oy0 + i, gj = ox0 + c;
        if (gi < OUT_H && gj < OUT_W) {
            float m1 = 0.f, m2 = 0.f, s11 = 0.f, s22 = 0.f, s12 = 0.f;
#pragma unroll
            for (int k = 0; k < WIN; ++k) {
                float wv = gw.w[k];
                m1  += wv * hb[0][i + k][c];
                m2  += wv * hb[1][i + k][c];
                s11 += wv * hb[2][i + k][c];
                s22 += wv * hb[3][i + k][c];
                s12 += wv * hb[4][i + k][c];
            }
            float mu1s = m1 * m1, mu2s = m2 * m2, mu12 = m1 * m2;
            float sig1 = s11 - mu1s;
            float sig2 = s22 - mu2s;
            float sig12 = s12 - mu12;
            float cs = (2.f * sig12 + C2F) / (sig1 + sig2 + C2F);
            cs = fmaxf(cs, 0.f);
            float ssim = (2.f * mu12 + C1F) / (mu1s + mu2s + C1F) * cs;
            psum += ssim;
        }
    }

    // ---- 4. block reduction (wave shuffle, then cross-wave via LDS) ----
#pragma unroll
    for (int off = 32; off > 0; off >>= 1)
        psum += __shfl_down(psum, off, 64);
    __shared__ float wsum[4];
    if ((tid & 63) == 0) wsum[tid >> 6] = psum;
    __syncthreads();
    if (tid == 0) {
        float s = wsum[0] + wsum[1] + wsum[2] + wsum[3];
        atomicAdd(acc, (double)s);
    }
}

__global__ void ssim_finalize_kernel(const double* __restrict__ acc,
                                     float* __restrict__ out)
{
    if (threadIdx.x == 0 && blockIdx.x == 0) {
        const double count = (double)96 * OUT_H * OUT_W;
        out[0] = (float)(1.0 - (*acc) / count);
    }
}

extern "C" void kernel_launch(void* const* d_in, const int* in_sizes, int n_in,
                              void* d_out, int out_size, void* d_ws, size_t ws_size,
                              hipStream_t stream) {
    (void)in_sizes; (void)n_in; (void)out_size; (void)ws_size;
    const float* X = (const float*)d_in[0];
    const float* Y = (const float*)d_in[1];
    // d_in[2] (win) unused: we recompute the separable 1D weights exactly as
    // the reference builds the 2D kernel (outer(g,g)/sum == outer(g/s, g/s)).
    float* out = (float*)d_out;
    double* acc = (double*)d_ws;

    hipMemsetAsync(d_ws, 0, sizeof(double), stream);

    GaussW gw;
    {
        double g[WIN], s = 0.0;
        for (int i = 0; i < WIN; ++i) {
            double d = (double)(i - 5);
            g[i] = exp(-(d * d) / (2.0 * 1.5 * 1.5));
            s += g[i];
        }
        for (int i = 0; i < WIN; ++i) gw.w[i] = (float)(g[i] / s);
    }

    dim3 grid((OUT_W + TO - 1) / TO, (OUT_H + TO - 1) / TO, 96);
    ssim_tile_kernel<<<grid, 256, 0, stream>>>(X, Y, gw, acc);
    ssim_finalize_kernel<<<1, 64, 0, stream>>>(acc, out);
}

// Round 2
// 314.838 us; speedup vs baseline: 1.4807x; 1.4807x over previous
//
#include <hip/hip_runtime.h>
#include <math.h>

// SSIM loss, (32,3,512,512) fp32, 11x11 sigma=1.5 Gaussian, VALID conv.
// R1 analysis: previous kernel was LDS-issue-bound (~376 scalar ds ops/wave
// ~= 348 us model vs 326 us measured). This version:
//   - vertical pass FIRST, reading global directly (lane-per-column =>
//     coalesced), scatter-accumulating 8 output rows x 5 fields in registers
//   - only the vertically-filtered fields go to LDS (one round trip)
//   - horizontal pass reads contiguous floats via ds_read_b128 (float4)
//   - SSIM pointwise + block reduce + one double atomic per block
// ds instr/wave drops ~376 -> ~71.

#define WIN   11
#define IMG   512
#define OUT_N 502
#define TO_R  32              // output rows per block
#define TO_C  64              // output cols per block
#define TI_R  (TO_R + WIN - 1)   // 42 input rows
#define TI_C  (TO_C + WIN - 1)   // 74 input cols
#define VB_W  76              // padded row stride (74+2), keeps 16B align
#define C1F   6.5025f
#define C2F   58.5225f

struct GaussW { float w[WIN]; };

__global__ __launch_bounds__(256) void ssim_v2_kernel(
    const float* __restrict__ X, const float* __restrict__ Y,
    GaussW gw, double* __restrict__ acc)
{
    // vertically filtered fields: [field][out_row][col]
    __shared__ float vb[5][TO_R][VB_W];   // 5*32*76*4 = 48640 B -> 3 blocks/CU

    const int plane = blockIdx.z;
    const int ox0 = blockIdx.x * TO_C;
    const int oy0 = blockIdx.y * TO_R;
    const float* Xp = X + (size_t)plane * IMG * IMG;
    const float* Yp = Y + (size_t)plane * IMG * IMG;
    const int tid = threadIdx.x;

    // ---- Phase 1: vertical 11-tap pass, register scatter-accumulate ----
    // 4 strips of 8 output rows x 74 cols = 296 items; lane-per-column =>
    // coalesced global loads down the column.
    for (int item = tid; item < 4 * TI_C; item += 256) {
        const int s = item / TI_C;          // strip 0..3
        const int c = item - s * TI_C;      // col 0..73
        int gc = ox0 + c; if (gc > IMG - 1) gc = IMG - 1;
        const int r0 = oy0 + s * 8;         // first input row of strip

        float a0[8] = {0}, a1[8] = {0}, a2[8] = {0}, a3[8] = {0}, a4[8] = {0};
#pragma unroll
        for (int k = 0; k < 18; ++k) {      // 8 outputs need 18 input rows
            int gr = r0 + k; if (gr > IMG - 1) gr = IMG - 1;
            size_t off = (size_t)gr * IMG + gc;
            float x = Xp[off];
            float y = Yp[off];
            float xx = x * x, yy = y * y, xy = x * y;
            const int jlo = (k > 10) ? (k - 10) : 0;
            const int jhi = (k < 7) ? k : 7;
#pragma unroll
            for (int j = jlo; j <= jhi; ++j) {
                float wv = gw.w[k - j];
                a0[j] += wv * x;
                a1[j] += wv * y;
                a2[j] += wv * xx;
                a3[j] += wv * yy;
                a4[j] += wv * xy;
            }
        }
#pragma unroll
        for (int j = 0; j < 8; ++j) {
            int i = s * 8 + j;
            vb[0][i][c] = a0[j];
            vb[1][i][c] = a1[j];
            vb[2][i][c] = a2[j];
            vb[3][i][c] = a3[j];
            vb[4][i][c] = a4[j];
        }
    }
    __syncthreads();

    // ---- Phase 2: horizontal 11-tap pass + SSIM pointwise ----
    // thread -> (row i, 8 consecutive cols); reads 20 contiguous floats per
    // field as 5x float4 (ds_read_b128).
    const int i  = tid >> 3;                // 0..31
    const int c0 = (tid & 7) * 8;           // 0,8,...,56
    float m[5][8];
#pragma unroll
    for (int f = 0; f < 5; ++f) {
        float v[20];
        const float4* p = (const float4*)&vb[f][i][c0];
#pragma unroll
        for (int q = 0; q < 5; ++q) {
            float4 t = p[q];
            v[4 * q + 0] = t.x; v[4 * q + 1] = t.y;
            v[4 * q + 2] = t.z; v[4 * q + 3] = t.w;
        }
#pragma unroll
        for (int j = 0; j < 8; ++j) {
            float s = 0.f;
#pragma unroll
            for (int k = 0; k < WIN; ++k) s += gw.w[k] * v[j + k];
            m[f][j] = s;
        }
    }

    float psum = 0.f;
    const int gi = oy0 + i;
#pragma unroll
    for (int j = 0; j < 8; ++j) {
        int gj = ox0 + c0 + j;
        if (gi < OUT_N && gj < OUT_N) {
            float m1 = m[0][j], m2 = m[1][j];
            float mu1s = m1 * m1, mu2s = m2 * m2, mu12 = m1 * m2;
            float sig1 = m[2][j] - mu1s;
            float sig2 = m[3][j] - mu2s;
            float sig12 = m[4][j] - mu12;
            float cs = (2.f * sig12 + C2F) / (sig1 + sig2 + C2F);
            cs = fmaxf(cs, 0.f);
            psum += (2.f * mu12 + C1F) / (mu1s + mu2s + C1F) * cs;
        }
    }

    // ---- block reduction ----
#pragma unroll
    for (int off = 32; off > 0; off >>= 1)
        psum += __shfl_down(psum, off, 64);
    __shared__ float wsum[4];
    if ((tid & 63) == 0) wsum[tid >> 6] = psum;
    __syncthreads();
    if (tid == 0) {
        float s = wsum[0] + wsum[1] + wsum[2] + wsum[3];
        atomicAdd(acc, (double)s);
    }
}

__global__ void ssim_finalize_kernel(const double* __restrict__ acc,
                                     float* __restrict__ out)
{
    if (threadIdx.x == 0 && blockIdx.x == 0) {
        const double count = (double)96 * OUT_N * OUT_N;
        out[0] = (float)(1.0 - (*acc) / count);
    }
}

extern "C" void kernel_launch(void* const* d_in, const int* in_sizes, int n_in,
                              void* d_out, int out_size, void* d_ws, size_t ws_size,
                              hipStream_t stream) {
    (void)in_sizes; (void)n_in; (void)out_size; (void)ws_size;
    const float* X = (const float*)d_in[0];
    const float* Y = (const float*)d_in[1];
    float* out = (float*)d_out;
    double* acc = (double*)d_ws;

    hipMemsetAsync(d_ws, 0, sizeof(double), stream);

    GaussW gw;
    {
        double g[WIN], s = 0.0;
        for (int i = 0; i < WIN; ++i) {
            double d = (double)(i - 5);
            g[i] = exp(-(d * d) / (2.0 * 1.5 * 1.5));
            s += g[i];
        }
        for (int i = 0; i < WIN; ++i) gw.w[i] = (float)(g[i] / s);
    }

    dim3 grid((OUT_N + TO_C - 1) / TO_C,   // 8
              (OUT_N + TO_R - 1) / TO_R,   // 16
              96);
    ssim_v2_kernel<<<grid, 256, 0, stream>>>(X, Y, gw, acc);
    ssim_finalize_kernel<<<1, 64, 0, stream>>>(acc, out);
}